// Round 1
// baseline (606.801 us; speedup 1.0000x reference)
//
#include <hip/hip_runtime.h>

#define N_FEAT_IN 256
#define N_HID 256
#define N_OUT 128

// ---------------------------------------------------------------------------
// Edge dtype probe: reference edge_index is int64; harness doc says integers
// arrive as int32. Detect on-device: if the odd int32 words (upper halves of
// little-endian int64) of the first 2048 elements are ~all zero -> int64.
// ---------------------------------------------------------------------------
__global__ void detect_i64_kernel(const int* __restrict__ edges, int* __restrict__ flag) {
    __shared__ int s[256];
    int tid = threadIdx.x;
    int zeros = 0;
    for (int i = tid; i < 2048; i += 256) zeros += (edges[2 * i + 1] == 0) ? 1 : 0;
    s[tid] = zeros;
    __syncthreads();
    for (int off = 128; off; off >>= 1) {
        if (tid < off) s[tid] += s[tid + off];
        __syncthreads();
    }
    if (tid == 0) flag[0] = (s[0] > 1900) ? 1 : 0;
}

__global__ void convert_kernel(const void* __restrict__ edges, int E,
                               const int* __restrict__ flag,
                               int* __restrict__ src, int* __restrict__ dst) {
    int e = blockIdx.x * blockDim.x + threadIdx.x;
    if (e >= E) return;
    if (flag[0]) {
        const long long* p = (const long long*)edges;
        src[e] = (int)p[e];
        dst[e] = (int)p[(size_t)E + e];
    } else {
        const int* p = (const int*)edges;
        src[e] = p[e];
        dst[e] = p[(size_t)E + e];
    }
}

__global__ void count_kernel(const int* __restrict__ dst, int E, int* __restrict__ cnt) {
    int e = blockIdx.x * blockDim.x + threadIdx.x;
    if (e < E) atomicAdd(&cnt[dst[e]], 1);
}

// deg = in-degree + 1 (self loop); always >= 1 so dinv = rsqrt(deg)
__global__ void dinv_kernel(const int* __restrict__ cnt, int Nn, float* __restrict__ dinv) {
    int i = blockIdx.x * blockDim.x + threadIdx.x;
    if (i < Nn) dinv[i] = rsqrtf((float)(cnt[i] + 1));
}

// Single-block sequential-chunk exclusive scan over counts -> row_ptr, cursor
__global__ void scan_kernel(const int* __restrict__ cnt, int Nn,
                            int* __restrict__ rowp, int* __restrict__ cursor) {
    __shared__ int sd[1024];
    __shared__ int carry;
    const int tid = threadIdx.x;
    if (tid == 0) carry = 0;
    __syncthreads();
    for (int base = 0; base < Nn; base += 1024) {
        int i = base + tid;
        int v = (i < Nn) ? cnt[i] : 0;
        sd[tid] = v;
        __syncthreads();
        for (int off = 1; off < 1024; off <<= 1) {
            int t = (tid >= off) ? sd[tid - off] : 0;
            __syncthreads();
            sd[tid] += t;
            __syncthreads();
        }
        int excl = carry + sd[tid] - v;
        if (i < Nn) { rowp[i] = excl; cursor[i] = excl; }
        int total = sd[1023];
        __syncthreads();
        if (tid == 0) carry += total;
        __syncthreads();
    }
    if (threadIdx.x == 0) rowp[Nn] = carry;
}

__global__ void fill_kernel(const int* __restrict__ src, const int* __restrict__ dst, int E,
                            const float* __restrict__ dinv, int* __restrict__ cursor,
                            int* __restrict__ col, float* __restrict__ nrm) {
    int e = blockIdx.x * blockDim.x + threadIdx.x;
    if (e >= E) return;
    int s = src[e], d = dst[e];
    int pos = atomicAdd(&cursor[d], 1);
    col[pos] = s;
    nrm[pos] = dinv[s] * dinv[d];
}

// ---------------------------------------------------------------------------
// fp32 GEMM: C[M,N] = A[M,K] @ B[K,N]. BM=128, BN=64, BK=16, 256 threads,
// each thread 8x4. A staged transposed in LDS so fragment reads are float4.
// ---------------------------------------------------------------------------
__global__ __launch_bounds__(256) void gemm128x64_kernel(
    const float* __restrict__ A, const float* __restrict__ B, float* __restrict__ C,
    int M, int N, int K) {
    __shared__ float Ast[16][128];  // [k][m]
    __shared__ float Bs[16][64];    // [k][n]
    const int tid = threadIdx.x;
    const int bx = blockIdx.x;   // N / 64
    const int by = blockIdx.y;   // ceil(M / 128)
    const int tx = tid & 15;
    const int ty = tid >> 4;
    const int arow = tid >> 1;           // 0..127
    const int akoff = (tid & 1) * 8;     // 0 or 8
    const long arowg = (long)by * 128 + arow;
    const bool avalid = (arowg < M);
    const float* Ap = A + (size_t)(avalid ? arowg : 0) * K + akoff;
    const float* Bp = B + (size_t)(tid >> 4) * N + bx * 64 + (tid & 15) * 4;

    float acc[8][4];
#pragma unroll
    for (int i = 0; i < 8; i++)
#pragma unroll
        for (int j = 0; j < 4; j++) acc[i][j] = 0.f;

    for (int k0 = 0; k0 < K; k0 += 16) {
        float4 a0 = make_float4(0.f, 0.f, 0.f, 0.f);
        float4 a1v = make_float4(0.f, 0.f, 0.f, 0.f);
        if (avalid) {
            a0 = *(const float4*)(Ap + k0);
            a1v = *(const float4*)(Ap + k0 + 4);
        }
        float4 bv = *(const float4*)(Bp + (size_t)k0 * N);
        __syncthreads();  // previous iteration's LDS reads done
        Ast[akoff + 0][arow] = a0.x;
        Ast[akoff + 1][arow] = a0.y;
        Ast[akoff + 2][arow] = a0.z;
        Ast[akoff + 3][arow] = a0.w;
        Ast[akoff + 4][arow] = a1v.x;
        Ast[akoff + 5][arow] = a1v.y;
        Ast[akoff + 6][arow] = a1v.z;
        Ast[akoff + 7][arow] = a1v.w;
        *(float4*)&Bs[tid >> 4][(tid & 15) * 4] = bv;
        __syncthreads();
#pragma unroll
        for (int kk = 0; kk < 16; kk++) {
            float4 av0 = *(const float4*)&Ast[kk][ty * 8];
            float4 av1 = *(const float4*)&Ast[kk][ty * 8 + 4];
            float4 bq = *(const float4*)&Bs[kk][tx * 4];
            float a[8] = {av0.x, av0.y, av0.z, av0.w, av1.x, av1.y, av1.z, av1.w};
            float b[4] = {bq.x, bq.y, bq.z, bq.w};
#pragma unroll
            for (int i = 0; i < 8; i++)
#pragma unroll
                for (int j = 0; j < 4; j++) acc[i][j] += a[i] * b[j];
        }
    }
#pragma unroll
    for (int i = 0; i < 8; i++) {
        long row = (long)by * 128 + ty * 8 + i;
        if (row < M) {
            float4 o = make_float4(acc[i][0], acc[i][1], acc[i][2], acc[i][3]);
            *(float4*)&C[(size_t)row * N + bx * 64 + tx * 4] = o;
        }
    }
}

// ---------------------------------------------------------------------------
// CSR aggregation: out[dst] = bias + dinv[dst]^2*h[dst] + sum_e nrm[e]*h[col[e]]
// One block per destination node, one thread per feature column.
// ---------------------------------------------------------------------------
template <int C, bool RELU>
__global__ __launch_bounds__(C) void agg_kernel(
    const float* __restrict__ h, const int* __restrict__ rowp, const int* __restrict__ col,
    const float* __restrict__ nrm, const float* __restrict__ dinv,
    const float* __restrict__ bias, float* __restrict__ out, int Nn) {
    const int dst = blockIdx.x;
    const int tid = threadIdx.x;
    const float di = dinv[dst];
    float acc = di * di * h[(size_t)dst * C + tid];
    const int s = rowp[dst];
    const int e = rowp[dst + 1];
    for (int k = s; k < e; ++k) {
        const int src = col[k];
        acc += nrm[k] * h[(size_t)src * C + tid];
    }
    acc += bias[tid];
    if (RELU) acc = fmaxf(acc, 0.f);
    out[(size_t)dst * C + tid] = acc;
}

extern "C" void kernel_launch(void* const* d_in, const int* in_sizes, int n_in,
                              void* d_out, int out_size, void* d_ws, size_t ws_size,
                              hipStream_t stream) {
    const float* x = (const float*)d_in[0];
    const void* edges = d_in[1];
    const float* W1 = (const float*)d_in[2];
    const float* b1 = (const float*)d_in[3];
    const float* W2 = (const float*)d_in[4];
    const float* b2 = (const float*)d_in[5];
    float* out = (float*)d_out;

    const int Nn = in_sizes[0] / N_FEAT_IN;  // 50000
    const int E = in_sizes[1] / 2;           // 800000

    char* w = (char*)d_ws;
    size_t off = 0;
    auto alloc = [&](size_t bytes) -> void* {
        void* p = (void*)(w + off);
        off += (bytes + 255) & ~(size_t)255;
        return p;
    };
    int* flag = (int*)alloc(sizeof(int));
    int* srcI = (int*)alloc((size_t)E * 4);
    int* dstI = (int*)alloc((size_t)E * 4);
    int* cnt = (int*)alloc((size_t)Nn * 4);
    int* rowp = (int*)alloc(((size_t)Nn + 1) * 4);
    int* cursor = (int*)alloc((size_t)Nn * 4);
    int* col = (int*)alloc((size_t)E * 4);
    float* nrm = (float*)alloc((size_t)E * 4);
    float* dinv = (float*)alloc((size_t)Nn * 4);
    float* h = (float*)alloc((size_t)Nn * N_HID * 4);   // H1, then reused for H2
    float* a1 = (float*)alloc((size_t)Nn * N_HID * 4);  // relu(conv1)

    hipMemsetAsync(cnt, 0, (size_t)Nn * 4, stream);
    detect_i64_kernel<<<1, 256, 0, stream>>>((const int*)edges, flag);
    const int eb = (E + 255) / 256;
    convert_kernel<<<eb, 256, 0, stream>>>(edges, E, flag, srcI, dstI);
    count_kernel<<<eb, 256, 0, stream>>>(dstI, E, cnt);
    dinv_kernel<<<(Nn + 255) / 256, 256, 0, stream>>>(cnt, Nn, dinv);
    scan_kernel<<<1, 1024, 0, stream>>>(cnt, Nn, rowp, cursor);
    fill_kernel<<<eb, 256, 0, stream>>>(srcI, dstI, E, dinv, cursor, col, nrm);

    // Layer 1: h = x @ W1 ; a1 = relu(Agg(h) + b1)
    dim3 g1(N_HID / 64, (Nn + 127) / 128);
    gemm128x64_kernel<<<g1, 256, 0, stream>>>(x, W1, h, Nn, N_HID, N_FEAT_IN);
    agg_kernel<N_HID, true><<<Nn, N_HID, 0, stream>>>(h, rowp, col, nrm, dinv, b1, a1, Nn);

    // Layer 2: h2 = a1 @ W2 (reuse h buffer) ; out = Agg(h2) + b2
    dim3 g2(N_OUT / 64, (Nn + 127) / 128);
    gemm128x64_kernel<<<g2, 256, 0, stream>>>(a1, W2, h, Nn, N_OUT, N_HID);
    agg_kernel<N_OUT, false><<<Nn, N_OUT, 0, stream>>>(h, rowp, col, nrm, dinv, b2, out, Nn);
}

// Round 2
// 434.850 us; speedup vs baseline: 1.3954x; 1.3954x over previous
//
#include <hip/hip_runtime.h>

#define N_FEAT_IN 256
#define N_HID 256
#define N_OUT 128

// ---------------------------------------------------------------------------
// Edge dtype probe: reference edge_index is int64; harness doc says integers
// arrive as int32. Detect on-device: if the odd int32 words (upper halves of
// little-endian int64) of the first 2048 elements are ~all zero -> int64.
// ---------------------------------------------------------------------------
__global__ void detect_i64_kernel(const int* __restrict__ edges, int* __restrict__ flag) {
    __shared__ int s[256];
    int tid = threadIdx.x;
    int zeros = 0;
    for (int i = tid; i < 2048; i += 256) zeros += (edges[2 * i + 1] == 0) ? 1 : 0;
    s[tid] = zeros;
    __syncthreads();
    for (int off = 128; off; off >>= 1) {
        if (tid < off) s[tid] += s[tid + off];
        __syncthreads();
    }
    if (tid == 0) flag[0] = (s[0] > 1900) ? 1 : 0;
}

__global__ void convert_kernel(const void* __restrict__ edges, int E,
                               const int* __restrict__ flag,
                               int* __restrict__ src, int* __restrict__ dst) {
    int e = blockIdx.x * blockDim.x + threadIdx.x;
    if (e >= E) return;
    if (flag[0]) {
        const long long* p = (const long long*)edges;
        src[e] = (int)p[e];
        dst[e] = (int)p[(size_t)E + e];
    } else {
        const int* p = (const int*)edges;
        src[e] = p[e];
        dst[e] = p[(size_t)E + e];
    }
}

__global__ void count_kernel(const int* __restrict__ dst, int E, int* __restrict__ cnt) {
    int e = blockIdx.x * blockDim.x + threadIdx.x;
    if (e < E) atomicAdd(&cnt[dst[e]], 1);
}

// deg = in-degree + 1 (self loop); always >= 1 so dinv = rsqrt(deg)
__global__ void dinv_kernel(const int* __restrict__ cnt, int Nn, float* __restrict__ dinv) {
    int i = blockIdx.x * blockDim.x + threadIdx.x;
    if (i < Nn) dinv[i] = rsqrtf((float)(cnt[i] + 1));
}

// ---------------------------------------------------------------------------
// Hierarchical exclusive scan: per-block scan -> top scan of block sums ->
// add offsets. Replaces the serial single-block scan.
// ---------------------------------------------------------------------------
__global__ __launch_bounds__(256) void scan_block_kernel(
    const int* __restrict__ cnt, int Nn, int* __restrict__ rowp, int* __restrict__ bsum) {
    __shared__ int sd[256];
    const int tid = threadIdx.x;
    const int i = blockIdx.x * 256 + tid;
    const int v = (i < Nn) ? cnt[i] : 0;
    sd[tid] = v;
    __syncthreads();
    for (int off = 1; off < 256; off <<= 1) {
        int t = (tid >= off) ? sd[tid - off] : 0;
        __syncthreads();
        sd[tid] += t;
        __syncthreads();
    }
    if (i < Nn) rowp[i] = sd[tid] - v;  // exclusive within block
    if (tid == 255) bsum[blockIdx.x] = sd[255];
}

__global__ __launch_bounds__(256) void scan_top_kernel(
    int* __restrict__ bsum, int Nb, int* __restrict__ rowp, int Nn) {
    __shared__ int sd[256];
    const int tid = threadIdx.x;
    const int v = (tid < Nb) ? bsum[tid] : 0;
    sd[tid] = v;
    __syncthreads();
    for (int off = 1; off < 256; off <<= 1) {
        int t = (tid >= off) ? sd[tid - off] : 0;
        __syncthreads();
        sd[tid] += t;
        __syncthreads();
    }
    if (tid < Nb) bsum[tid] = sd[tid] - v;  // exclusive block offsets
    if (tid == 255) rowp[Nn] = sd[255];     // grand total
}

__global__ __launch_bounds__(256) void scan_add_kernel(
    const int* __restrict__ bsum, int Nn, int* __restrict__ rowp, int* __restrict__ cursor) {
    const int i = blockIdx.x * 256 + threadIdx.x;
    if (i < Nn) {
        const int r = rowp[i] + bsum[i >> 8];
        rowp[i] = r;
        cursor[i] = r;
    }
}

__global__ void fill_kernel(const int* __restrict__ src, const int* __restrict__ dst, int E,
                            const float* __restrict__ dinv, int* __restrict__ cursor,
                            int* __restrict__ col, float* __restrict__ nrm) {
    int e = blockIdx.x * blockDim.x + threadIdx.x;
    if (e >= E) return;
    int s = src[e], d = dst[e];
    int pos = atomicAdd(&cursor[d], 1);
    col[pos] = s;
    nrm[pos] = dinv[s] * dinv[d];
}

// ---------------------------------------------------------------------------
// fp32 GEMM: C[M,N] = A[M,K] @ B[K,N]. BM=128, BN=64, BK=16, 256 threads,
// each thread 8x4. A staged transposed in LDS so fragment reads are float4.
// ---------------------------------------------------------------------------
__global__ __launch_bounds__(256) void gemm128x64_kernel(
    const float* __restrict__ A, const float* __restrict__ B, float* __restrict__ C,
    int M, int N, int K) {
    __shared__ float Ast[16][128];  // [k][m]
    __shared__ float Bs[16][64];    // [k][n]
    const int tid = threadIdx.x;
    const int bx = blockIdx.x;   // N / 64
    const int by = blockIdx.y;   // ceil(M / 128)
    const int tx = tid & 15;
    const int ty = tid >> 4;
    const int arow = tid >> 1;           // 0..127
    const int akoff = (tid & 1) * 8;     // 0 or 8
    const long arowg = (long)by * 128 + arow;
    const bool avalid = (arowg < M);
    const float* Ap = A + (size_t)(avalid ? arowg : 0) * K + akoff;
    const float* Bp = B + (size_t)(tid >> 4) * N + bx * 64 + (tid & 15) * 4;

    float acc[8][4];
#pragma unroll
    for (int i = 0; i < 8; i++)
#pragma unroll
        for (int j = 0; j < 4; j++) acc[i][j] = 0.f;

    for (int k0 = 0; k0 < K; k0 += 16) {
        float4 a0 = make_float4(0.f, 0.f, 0.f, 0.f);
        float4 a1v = make_float4(0.f, 0.f, 0.f, 0.f);
        if (avalid) {
            a0 = *(const float4*)(Ap + k0);
            a1v = *(const float4*)(Ap + k0 + 4);
        }
        float4 bv = *(const float4*)(Bp + (size_t)k0 * N);
        __syncthreads();  // previous iteration's LDS reads done
        Ast[akoff + 0][arow] = a0.x;
        Ast[akoff + 1][arow] = a0.y;
        Ast[akoff + 2][arow] = a0.z;
        Ast[akoff + 3][arow] = a0.w;
        Ast[akoff + 4][arow] = a1v.x;
        Ast[akoff + 5][arow] = a1v.y;
        Ast[akoff + 6][arow] = a1v.z;
        Ast[akoff + 7][arow] = a1v.w;
        *(float4*)&Bs[tid >> 4][(tid & 15) * 4] = bv;
        __syncthreads();
#pragma unroll
        for (int kk = 0; kk < 16; kk++) {
            float4 av0 = *(const float4*)&Ast[kk][ty * 8];
            float4 av1 = *(const float4*)&Ast[kk][ty * 8 + 4];
            float4 bq = *(const float4*)&Bs[kk][tx * 4];
            float a[8] = {av0.x, av0.y, av0.z, av0.w, av1.x, av1.y, av1.z, av1.w};
            float b[4] = {bq.x, bq.y, bq.z, bq.w};
#pragma unroll
            for (int i = 0; i < 8; i++)
#pragma unroll
                for (int j = 0; j < 4; j++) acc[i][j] += a[i] * b[j];
        }
    }
#pragma unroll
    for (int i = 0; i < 8; i++) {
        long row = (long)by * 128 + ty * 8 + i;
        if (row < M) {
            float4 o = make_float4(acc[i][0], acc[i][1], acc[i][2], acc[i][3]);
            *(float4*)&C[(size_t)row * N + bx * 64 + tx * 4] = o;
        }
    }
}

// ---------------------------------------------------------------------------
// CSR aggregation, wave-per-node, vectorized:
// out[dst] = bias + dinv[dst]^2*h[dst] + sum_e nrm[e]*h[col[e]]
// Lane l owns columns [VEC*l, VEC*l+VEC): float4 for C=256, float2 for C=128.
// node made wave-uniform so rowp/col/nrm go through the scalar pipe.
// ---------------------------------------------------------------------------
template <int C, bool RELU>
__global__ __launch_bounds__(256) void agg_kernel(
    const float* __restrict__ h, const int* __restrict__ rowp, const int* __restrict__ col,
    const float* __restrict__ nrm, const float* __restrict__ dinv,
    const float* __restrict__ bias, float* __restrict__ out, int Nn) {
    constexpr int VEC = C / 64;
    static_assert(VEC == 2 || VEC == 4, "C must be 128 or 256");
    const int lane = threadIdx.x & 63;
    const int wv = threadIdx.x >> 6;
    const int node0 = blockIdx.x * 4 + wv;
    if (node0 >= Nn) return;
    const int node = __builtin_amdgcn_readfirstlane(node0);
    const float di = dinv[node];
    const int coff = lane * VEC;
    float acc[VEC];
    {
        const float* r = h + (size_t)node * C + coff;
        if constexpr (VEC == 4) {
            float4 v = *(const float4*)r;
            acc[0] = di * di * v.x; acc[1] = di * di * v.y;
            acc[2] = di * di * v.z; acc[3] = di * di * v.w;
        } else {
            float2 v = *(const float2*)r;
            acc[0] = di * di * v.x; acc[1] = di * di * v.y;
        }
    }
    const int s = rowp[node];
    const int e = rowp[node + 1];
    for (int k = s; k < e; ++k) {
        const int src = col[k];
        const float w = nrm[k];
        const float* r = h + (size_t)src * C + coff;
        if constexpr (VEC == 4) {
            float4 v = *(const float4*)r;
            acc[0] += w * v.x; acc[1] += w * v.y;
            acc[2] += w * v.z; acc[3] += w * v.w;
        } else {
            float2 v = *(const float2*)r;
            acc[0] += w * v.x; acc[1] += w * v.y;
        }
    }
    float* o = out + (size_t)node * C + coff;
    if constexpr (VEC == 4) {
        float4 bv = *(const float4*)(bias + coff);
        float4 ov = make_float4(acc[0] + bv.x, acc[1] + bv.y, acc[2] + bv.z, acc[3] + bv.w);
        if (RELU) {
            ov.x = fmaxf(ov.x, 0.f); ov.y = fmaxf(ov.y, 0.f);
            ov.z = fmaxf(ov.z, 0.f); ov.w = fmaxf(ov.w, 0.f);
        }
        *(float4*)o = ov;
    } else {
        float2 bv = *(const float2*)(bias + coff);
        float2 ov = make_float2(acc[0] + bv.x, acc[1] + bv.y);
        if (RELU) { ov.x = fmaxf(ov.x, 0.f); ov.y = fmaxf(ov.y, 0.f); }
        *(float2*)o = ov;
    }
}

extern "C" void kernel_launch(void* const* d_in, const int* in_sizes, int n_in,
                              void* d_out, int out_size, void* d_ws, size_t ws_size,
                              hipStream_t stream) {
    const float* x = (const float*)d_in[0];
    const void* edges = d_in[1];
    const float* W1 = (const float*)d_in[2];
    const float* b1 = (const float*)d_in[3];
    const float* W2 = (const float*)d_in[4];
    const float* b2 = (const float*)d_in[5];
    float* out = (float*)d_out;

    const int Nn = in_sizes[0] / N_FEAT_IN;  // 50000
    const int E = in_sizes[1] / 2;           // 800000

    char* w = (char*)d_ws;
    size_t off = 0;
    auto alloc = [&](size_t bytes) -> void* {
        void* p = (void*)(w + off);
        off += (bytes + 255) & ~(size_t)255;
        return p;
    };
    int* flag = (int*)alloc(sizeof(int));
    int* srcI = (int*)alloc((size_t)E * 4);
    int* dstI = (int*)alloc((size_t)E * 4);
    int* cnt = (int*)alloc((size_t)Nn * 4);
    int* rowp = (int*)alloc(((size_t)Nn + 1) * 4);
    int* cursor = (int*)alloc((size_t)Nn * 4);
    int* bsum = (int*)alloc(1024 * 4);
    int* col = (int*)alloc((size_t)E * 4);
    float* nrm = (float*)alloc((size_t)E * 4);
    float* dinv = (float*)alloc((size_t)Nn * 4);
    float* h = (float*)alloc((size_t)Nn * N_HID * 4);   // H1, then reused for H2
    float* a1 = (float*)alloc((size_t)Nn * N_HID * 4);  // relu(conv1)

    hipMemsetAsync(cnt, 0, (size_t)Nn * 4, stream);
    detect_i64_kernel<<<1, 256, 0, stream>>>((const int*)edges, flag);
    const int eb = (E + 255) / 256;
    convert_kernel<<<eb, 256, 0, stream>>>(edges, E, flag, srcI, dstI);
    count_kernel<<<eb, 256, 0, stream>>>(dstI, E, cnt);
    dinv_kernel<<<(Nn + 255) / 256, 256, 0, stream>>>(cnt, Nn, dinv);
    const int nb = (Nn + 255) / 256;  // 196
    scan_block_kernel<<<nb, 256, 0, stream>>>(cnt, Nn, rowp, bsum);
    scan_top_kernel<<<1, 256, 0, stream>>>(bsum, nb, rowp, Nn);
    scan_add_kernel<<<nb, 256, 0, stream>>>(bsum, Nn, rowp, cursor);
    fill_kernel<<<eb, 256, 0, stream>>>(srcI, dstI, E, dinv, cursor, col, nrm);

    // Layer 1: h = x @ W1 ; a1 = relu(Agg(h) + b1)
    dim3 g1(N_HID / 64, (Nn + 127) / 128);
    gemm128x64_kernel<<<g1, 256, 0, stream>>>(x, W1, h, Nn, N_HID, N_FEAT_IN);
    agg_kernel<N_HID, true><<<(Nn + 3) / 4, 256, 0, stream>>>(h, rowp, col, nrm, dinv, b1, a1, Nn);

    // Layer 2: h2 = a1 @ W2 (reuse h buffer) ; out = Agg(h2) + b2
    dim3 g2(N_OUT / 64, (Nn + 127) / 128);
    gemm128x64_kernel<<<g2, 256, 0, stream>>>(a1, W2, h, Nn, N_OUT, N_HID);
    agg_kernel<N_OUT, false><<<(Nn + 3) / 4, 256, 0, stream>>>(h, rowp, col, nrm, dinv, b2, out, Nn);
}